// Round 4
// baseline (192.809 us; speedup 1.0000x reference)
//
#include <hip/hip_runtime.h>

// Problem constants (fixed by setup_inputs: B=2,C=32,H=128,W=240, max_disp=192 -> D=48)
constexpr int B  = 2;
constexpr int C  = 32;
constexpr int H  = 128;
constexpr int W  = 240;
constexpr int D  = 48;
constexpr int C2 = 2 * C;            // 64 output channels
constexpr int W4 = W / 4;            // 60 float4 per row
constexpr int QPS = H * W4;          // 7680 float4 per (b,c2,d) slice
constexpr int SLICES = B * C2 * D;   // 6144 blocks, one per contiguous output slice
constexpr int BLOCK = 256;
constexpr int KITER = QPS / BLOCK;   // 30 float4 stores per thread

// Right-half slice copy with compile-time sub-quad shift S = d & 3.
// Output quad at (row, w4) needs source floats [w0-d .. w0-d+3], spanning
// aligned quads Hi = w4-g and Lo = w4-g-1 (d = 4g + S); element j of the
// output is window[4 + j - S] where window = Lo||Hi.
// Negative quad indices are clamped to 0; the garbage provably feeds only
// mask-zeroed elements: Lo<0 => w4<=g => valid j needs j >= S+(4g-w0) >= S,
// but Lo-sourced elements have j < S; Hi<0 => w0 < 4g => valid j needs
// j >= S+4 — impossible.
template <int S>
__device__ __forceinline__ void right_slice(const float4* __restrict__ img,
                                            float4* __restrict__ o,
                                            int d, int g)
{
#pragma unroll 5
    for (int k = 0; k < KITER; ++k) {
        int idx = (int)threadIdx.x + k * BLOCK;
        int row = idx / W4;
        int w4  = idx - row * W4;
        int w0  = w4 * 4;
        int rowbase = row * W4;
        int qhi = w4 - g;
        int qlo = qhi - 1;
        float4 Hi = img[rowbase + (qhi < 0 ? 0 : qhi)];
        float4 Lo;
        if constexpr (S > 0) {
            Lo = img[rowbase + (qlo < 0 ? 0 : qlo)];
        } else {
            Lo = Hi;  // unused (window indices 4..7), keeps win[] defined
        }
        float win[8] = { Lo.x, Lo.y, Lo.z, Lo.w, Hi.x, Hi.y, Hi.z, Hi.w };
        float4 r;
        r.x = (w0 + 0 >= d) ? win[4 + 0 - S] : 0.0f;
        r.y = (w0 + 1 >= d) ? win[4 + 1 - S] : 0.0f;
        r.z = (w0 + 2 >= d) ? win[4 + 2 - S] : 0.0f;
        r.w = (w0 + 3 >= d) ? win[4 + 3 - S] : 0.0f;
        o[idx] = r;
    }
}

__global__ __launch_bounds__(256)
void cost_volume_kernel(const float* __restrict__ left,
                        const float* __restrict__ right,
                        float4* __restrict__ out)
{
    // blockIdx.x = (b*C2 + c2)*D + d  -> block writes one contiguous slice,
    // consecutive blocks write consecutive 120KB regions (fill-like stream).
    int slice = blockIdx.x;
    int d  = slice % D;
    int t  = slice / D;
    int c2 = t % C2;
    int b  = t / C2;

    float4* o = out + (size_t)slice * QPS;

    if (c2 < C) {
        // left half: masked copy; source quad index == dest quad index
        const float4* img = reinterpret_cast<const float4*>(
            left + (size_t)((b * C + c2) * H) * W);
#pragma unroll 5
        for (int k = 0; k < KITER; ++k) {
            int idx = (int)threadIdx.x + k * BLOCK;
            int row = idx / W4;
            int w0  = (idx - row * W4) * 4;
            float4 v = img[idx];
            float4 r;
            r.x = (w0 + 0 >= d) ? v.x : 0.0f;
            r.y = (w0 + 1 >= d) ? v.y : 0.0f;
            r.z = (w0 + 2 >= d) ? v.z : 0.0f;
            r.w = (w0 + 3 >= d) ? v.w : 0.0f;
            o[idx] = r;
        }
    } else {
        const float4* img = reinterpret_cast<const float4*>(
            right + (size_t)((b * C + (c2 - C)) * H) * W);
        int g = d >> 2;
        switch (d & 3) {
            case 0: right_slice<0>(img, o, d, g); break;
            case 1: right_slice<1>(img, o, d, g); break;
            case 2: right_slice<2>(img, o, d, g); break;
            case 3: right_slice<3>(img, o, d, g); break;
        }
    }
}

extern "C" void kernel_launch(void* const* d_in, const int* in_sizes, int n_in,
                              void* d_out, int out_size, void* d_ws, size_t ws_size,
                              hipStream_t stream)
{
    const float* left  = (const float*)d_in[0];
    const float* right = (const float*)d_in[1];
    float4* out = (float4*)d_out;

    cost_volume_kernel<<<SLICES, BLOCK, 0, stream>>>(left, right, out);
}

// Round 6
// 143.263 us; speedup vs baseline: 1.3458x; 1.3458x over previous
//
#include <hip/hip_runtime.h>

// Problem constants (fixed by setup_inputs: B=2,C=32,H=128,W=240, max_disp=192 -> D=48)
constexpr int B  = 2;
constexpr int C  = 32;
constexpr int H  = 128;
constexpr int W  = 240;
constexpr int D  = 48;
constexpr int C2 = 2 * C;            // 64 output channels
constexpr int W4 = W / 4;            // 60 float4 per row
constexpr int DSTRIDE = H * W4;      // float4 stride between consecutive d slices
constexpr int NT = B * C2 * H * W4;  // 983,040 threads (one per (b,c2,h,w4))

// native vector type for __builtin_nontemporal_store (HIP_vector_type is rejected)
typedef float nfloat4 __attribute__((ext_vector_type(4)));

__device__ __forceinline__ void nt_store(float4* p, float x, float y, float z, float w)
{
    nfloat4 v = { x, y, z, w };
    __builtin_nontemporal_store(v, reinterpret_cast<nfloat4*>(p));
}

__global__ __launch_bounds__(256)
void cost_volume_kernel(const float* __restrict__ left,
                        const float* __restrict__ right,
                        float4* __restrict__ out)
{
    int v = blockIdx.x * blockDim.x + threadIdx.x;
    if (v >= NT) return;

    int w4 = v % W4;
    int t  = v / W4;
    int h  = t % H;  t /= H;
    int c2 = t % C2;
    int b  = t / C2;
    int w0 = w4 * 4;

    // out float4 index = (((b*C2 + c2)*D + d)*H + h)*W4 + w4
    float4* outp = out + ((b * C2 + c2) * D * H + h) * W4 + w4;

    if (c2 < C) {
        // ---- left volume: one load, 48 masked nontemporal stores ----
        const float* src = left + ((b * C + c2) * H + h) * W;
        float4 vv = *reinterpret_cast<const float4*>(src + w0);
#pragma unroll
        for (int d = 0; d < D; ++d) {
            nt_store(outp + d * DSTRIDE,
                     (w0 + 0 >= d) ? vv.x : 0.0f,
                     (w0 + 1 >= d) ? vv.y : 0.0f,
                     (w0 + 2 >= d) ? vv.z : 0.0f,
                     (w0 + 3 >= d) ? vv.w : 0.0f);
        }
    } else {
        // ---- right volume: 4 disparities per aligned float4 load ----
        // d-group g covers d = 4g..4g+3; output elem j at disparity d needs
        // srow[w0 + j - d], spanning aligned quads A = q(w4-g), B = q(w4-g-1).
        // window[0..3] = B, window[4..7] = A; elem j at shift s=d-4g is
        // window[4 + j - s] (compile-time index after unroll).
        // Quad indices < 0 are clamped to 0: every element so poisoned feeds
        // only mask-zeroed outputs.
        const float* srow = right + ((b * C + (c2 - C)) * H + h) * W;
        float4 A = *reinterpret_cast<const float4*>(srow + w0);  // q(w4), g=0
#pragma unroll
        for (int g = 0; g < D / 4; ++g) {
            int qb = w4 - g - 1;
            int qbc = qb < 0 ? 0 : qb;
            float4 Bq = *reinterpret_cast<const float4*>(srow + 4 * qbc);
            float win[8] = { Bq.x, Bq.y, Bq.z, Bq.w, A.x, A.y, A.z, A.w };
#pragma unroll
            for (int s = 0; s < 4; ++s) {
                const int d = 4 * g + s;
                nt_store(outp + d * DSTRIDE,
                         (w0 + 0 >= d) ? win[4 + 0 - s] : 0.0f,
                         (w0 + 1 >= d) ? win[4 + 1 - s] : 0.0f,
                         (w0 + 2 >= d) ? win[4 + 2 - s] : 0.0f,
                         (w0 + 3 >= d) ? win[4 + 3 - s] : 0.0f);
            }
            A = Bq;  // next group's high quad is this group's low quad
        }
    }
}

extern "C" void kernel_launch(void* const* d_in, const int* in_sizes, int n_in,
                              void* d_out, int out_size, void* d_ws, size_t ws_size,
                              hipStream_t stream)
{
    const float* left  = (const float*)d_in[0];
    const float* right = (const float*)d_in[1];
    float4* out = (float4*)d_out;

    constexpr int BLOCK = 256;
    constexpr int GRID  = (NT + BLOCK - 1) / BLOCK;  // 3840 blocks
    cost_volume_kernel<<<GRID, BLOCK, 0, stream>>>(left, right, out);
}

// Round 7
// 142.334 us; speedup vs baseline: 1.3546x; 1.0065x over previous
//
#include <hip/hip_runtime.h>

// Problem constants (fixed by setup_inputs: B=2,C=32,H=128,W=240, max_disp=192 -> D=48)
constexpr int B  = 2;
constexpr int C  = 32;
constexpr int H  = 128;
constexpr int W  = 240;
constexpr int D  = 48;
constexpr int C2 = 2 * C;            // 64 output channels
constexpr int W4 = W / 4;            // 60 float4 per row
constexpr int DSTRIDE = H * W4;      // float4 stride between consecutive d slices
constexpr int NPLANES = B * C2;      // 128 (b,c2) planes
constexpr int BPP = H * W4 / 256;    // 30 blocks per plane
constexpr int NXCD = 8;
constexpr int PPX = NPLANES / NXCD;  // 16 planes per XCD
constexpr int GRID = NPLANES * BPP;  // 3840 blocks

// native vector type for __builtin_nontemporal_store (HIP_vector_type is rejected)
typedef float nfloat4 __attribute__((ext_vector_type(4)));

__device__ __forceinline__ void nt_store(float4* p, float x, float y, float z, float w)
{
    nfloat4 v = { x, y, z, w };
    __builtin_nontemporal_store(v, reinterpret_cast<nfloat4*>(p));
}

__global__ __launch_bounds__(256)
void cost_volume_kernel(const float* __restrict__ left,
                        const float* __restrict__ right,
                        float4* __restrict__ out)
{
    // XCD-partitioned plane assignment: dispatch round-robins XCDs by
    // blockIdx%8, so give XCD x the 16 complete (b,c2) planes
    // [x*16, x*16+16) — each input plane is HBM-fetched by exactly one
    // XCD L2 (16 planes * 120KB = 1.9MB <= 4MB), killing the 8x read
    // replication. Perf heuristic only; correctness is mapping-independent.
    int bid   = blockIdx.x;
    int xcd   = bid & (NXCD - 1);
    int j     = bid >> 3;              // 0..479
    int plane = xcd * PPX + j / BPP;   // 0..127
    int inner = j % BPP;               // 0..29
    int c2    = plane & (C2 - 1);
    int b     = plane >> 6;

    int q  = inner * 256 + (int)threadIdx.x;  // quad index in plane, 0..7679
    int h  = q / W4;
    int w4 = q - h * W4;
    int w0 = w4 * 4;

    // out float4 index = (((b*C2 + c2)*D + d)*H + h)*W4 + w4
    float4* outp = out + ((b * C2 + c2) * D * H + h) * W4 + w4;

    if (c2 < C) {
        // ---- left volume: one load, 48 masked nontemporal stores ----
        const float* src = left + ((b * C + c2) * H + h) * W;
        float4 vv = *reinterpret_cast<const float4*>(src + w0);
#pragma unroll
        for (int d = 0; d < D; ++d) {
            nt_store(outp + d * DSTRIDE,
                     (w0 + 0 >= d) ? vv.x : 0.0f,
                     (w0 + 1 >= d) ? vv.y : 0.0f,
                     (w0 + 2 >= d) ? vv.z : 0.0f,
                     (w0 + 3 >= d) ? vv.w : 0.0f);
        }
    } else {
        // ---- right volume: 4 disparities per aligned float4 load ----
        // d-group g covers d = 4g..4g+3; output elem j at disparity d needs
        // srow[w0 + j - d], spanning aligned quads A = q(w4-g), B = q(w4-g-1).
        // window[0..3] = B, window[4..7] = A; elem j at shift s=d-4g is
        // window[4 + j - s] (compile-time index after unroll).
        // Quad indices < 0 are clamped to 0: every element so poisoned feeds
        // only mask-zeroed outputs.
        const float* srow = right + ((b * C + (c2 - C)) * H + h) * W;
        float4 A = *reinterpret_cast<const float4*>(srow + w0);  // q(w4), g=0
#pragma unroll
        for (int g = 0; g < D / 4; ++g) {
            int qb = w4 - g - 1;
            int qbc = qb < 0 ? 0 : qb;
            float4 Bq = *reinterpret_cast<const float4*>(srow + 4 * qbc);
            float win[8] = { Bq.x, Bq.y, Bq.z, Bq.w, A.x, A.y, A.z, A.w };
#pragma unroll
            for (int s = 0; s < 4; ++s) {
                const int d = 4 * g + s;
                nt_store(outp + d * DSTRIDE,
                         (w0 + 0 >= d) ? win[4 + 0 - s] : 0.0f,
                         (w0 + 1 >= d) ? win[4 + 1 - s] : 0.0f,
                         (w0 + 2 >= d) ? win[4 + 2 - s] : 0.0f,
                         (w0 + 3 >= d) ? win[4 + 3 - s] : 0.0f);
            }
            A = Bq;  // next group's high quad is this group's low quad
        }
    }
}

extern "C" void kernel_launch(void* const* d_in, const int* in_sizes, int n_in,
                              void* d_out, int out_size, void* d_ws, size_t ws_size,
                              hipStream_t stream)
{
    const float* left  = (const float*)d_in[0];
    const float* right = (const float*)d_in[1];
    float4* out = (float4*)d_out;

    cost_volume_kernel<<<GRID, 256, 0, stream>>>(left, right, out);
}